// Round 10
// baseline (346.261 us; speedup 1.0000x reference)
//
#include <hip/hip_runtime.h>
#include <stdint.h>

// Transformer block: x + attn(rmsnorm(x)) then + swiglu(rmsnorm(.))
// bf16 MFMA (16x16x32), fp32 accumulate, fp32 residuals.
// B=2, L=2048, D=1024, H=16, DK=64, FF=2730 (padded to 2816).

#define LSEQ   2048
#define DMODEL 1024
#define NHEAD  16
#define NTOK   4096
#define FFR    2730
#define FFP    2816
#define FF2    5632          // w1|w3 fused N (interleaved in 32-row units)

typedef short  short8  __attribute__((ext_vector_type(8)));
typedef float  floatx4 __attribute__((ext_vector_type(4)));

__device__ __forceinline__ uint16_t f2bf(float f) {
  uint32_t u = __builtin_bit_cast(uint32_t, f);
  u += 0x7FFFu + ((u >> 16) & 1u);          // RNE
  return (uint16_t)(u >> 16);
}
// v_cvt_pk_bf16_f32: low=a, high=b. Proven bit-identical to explicit RNE pack
// (rounds 1/2 produced identical outputs with cvt_pk vs explicit f2bf pack).
__device__ __forceinline__ uint32_t cvt_pk_bf16(float a, float b) {
  uint32_t d;
  asm("v_cvt_pk_bf16_f32 %0, %1, %2" : "=v"(d) : "v"(a), "v"(b));
  return d;
}
__device__ __forceinline__ void gl2lds16(const void* g, void* l) {
  __builtin_amdgcn_global_load_lds(
      (const __attribute__((address_space(1))) unsigned int*)g,
      (__attribute__((address_space(3))) unsigned int*)l, 16, 0, 0);
}
// counted VMEM wait (T4). Literal-only asm string, if constexpr dispatch.
template <int N>
__device__ __forceinline__ void vm_wait() {
  if constexpr (N == 0)      asm volatile("s_waitcnt vmcnt(0)" ::: "memory");
  else if constexpr (N == 3) asm volatile("s_waitcnt vmcnt(3)" ::: "memory");
  else if constexpr (N == 4) asm volatile("s_waitcnt vmcnt(4)" ::: "memory");
}

// ------------------------------------------------ fused weight convert
// dst rows: [0,3072) wqkv | [3072,4096) wo |
// [4096,9728) w13 interleaved: unit u (64 rows) = [w1 rows u*32..+31 | w3 rows u*32..+31]
__global__ __launch_bounds__(256) void cvt_all_k(const float* __restrict__ wqkv,
                                                 const float* __restrict__ wo,
                                                 const float* __restrict__ w1,
                                                 const float* __restrict__ w3,
                                                 uint16_t* __restrict__ dst) {
  int g = blockIdx.x;                 // one row (1024 cols) per block
  int c = threadIdx.x * 4;
  const float* src = nullptr;
  if (g < 3072)       src = wqkv + (size_t)g * 1024;
  else if (g < 4096)  src = wo + (size_t)(g - 3072) * 1024;
  else {
    int r = g - 4096;                 // 0..5631
    int u = r >> 6, wi = r & 63;
    int srow = u * 32 + (wi & 31);
    if (srow < FFR) src = ((wi < 32) ? w1 : w3) + (size_t)srow * 1024;
  }
  float4 v = src ? *(const float4*)(src + c) : float4{0, 0, 0, 0};
  uint64_t pack =  (uint64_t)f2bf(v.x)        | ((uint64_t)f2bf(v.y) << 16)
                | ((uint64_t)f2bf(v.z) << 32) | ((uint64_t)f2bf(v.w) << 48);
  *(uint64_t*)(dst + (size_t)g * 1024 + c) = pack;
}

// w2 needs column padding 2730->2816; 4 cols/thread, uint64 store.
__global__ __launch_bounds__(256) void cvt_pad_k(const float* __restrict__ src,
                                                 uint16_t* __restrict__ dst,
                                                 int rows, int cols, int cols_p) {
  long idx = (long)blockIdx.x * 256 + threadIdx.x;   // one per 4 cols
  int c4 = cols_p >> 2;
  if (idx >= (long)rows * c4) return;
  int r = (int)(idx / c4);
  int c = (int)(idx % c4) * 4;
  uint64_t pack;
  if (c + 3 < cols) {
    const float* sp = src + (size_t)r * cols + c;
    float2 a = *(const float2*)sp;
    float2 b2 = *(const float2*)(sp + 2);
    pack =  (uint64_t)f2bf(a.x)        | ((uint64_t)f2bf(a.y) << 16)
         | ((uint64_t)f2bf(b2.x) << 32) | ((uint64_t)f2bf(b2.y) << 48);
  } else {
    pack = 0;
    for (int e = 0; e < 4; e++) {
      float v = (c + e < cols) ? src[(size_t)r * cols + c + e] : 0.0f;
      pack |= (uint64_t)f2bf(v) << (16 * e);
    }
  }
  *(uint64_t*)(dst + (size_t)r * cols_p + c) = pack;
}

// ---------------------------------------------------------------- rmsnorm
__global__ __launch_bounds__(256) void rmsnorm_k(const float* __restrict__ x,
                                                 const float* __restrict__ wgt,
                                                 uint16_t* __restrict__ out) {
  const int row = blockIdx.x;
  const int c = threadIdx.x * 4;
  const float* xr = x + (size_t)row * DMODEL;
  float4 v = *(const float4*)(xr + c);
  float ss = v.x * v.x + v.y * v.y + v.z * v.z + v.w * v.w;
#pragma unroll
  for (int off = 32; off >= 1; off >>= 1) ss += __shfl_down(ss, off, 64);
  __shared__ float red[4];
  if ((threadIdx.x & 63) == 0) red[threadIdx.x >> 6] = ss;
  __syncthreads();
  float tot = red[0] + red[1] + red[2] + red[3];
  float scale = rsqrtf(tot * (1.0f / DMODEL) + 1e-6f);
  float4 wv = *(const float4*)(wgt + c);
  uint64_t pack =  (uint64_t)f2bf(v.x * scale * wv.x)
                | ((uint64_t)f2bf(v.y * scale * wv.y) << 16)
                | ((uint64_t)f2bf(v.z * scale * wv.z) << 32)
                | ((uint64_t)f2bf(v.w * scale * wv.w) << 48);
  *(uint64_t*)(out + (size_t)row * DMODEL + c) = pack;
}

// ---------------------------------------------------------------- GEMM
// C[M,N] = A[M,K](bf16,row) @ B[N,K](bf16,row)^T ; tile TM x TN, 4 waves (2x2).
// MODE 0: bf16 store. MODE 1: fp32 Cf = acc + Res.
// MODE 2 (TN=128): B rows interleaved w1/w3 in 32-row units; epilogue computes
//   silu(a)*b in-register, writes bf16 to Cb with row stride N/2.
// T4 pipeline (counted vmcnt, m218 mechanism): double-buffered LDS, raw
// s_barrier (no vmcnt(0) drain in the loop). Verified r9: 368.6->341.1us.
template <int MODE, int TM, int TN>
__global__ __launch_bounds__(256) void gemm_bt(const uint16_t* __restrict__ A,
                                               const uint16_t* __restrict__ B,
                                               uint16_t* __restrict__ Cb,
                                               float* __restrict__ Cf,
                                               const float* __restrict__ Res,
                                               int M, int N, int K) {
  constexpr int FI = TM / 32, FJ = TN / 32;
  constexpr int NIT = (TM + TN) / 64;
  constexpr int BUFO = (TM + TN) * 32;       // uint16 elems per buffer
  __shared__ uint16_t S[2 * BUFO];           // [buf][A(TM*32) | B(TN*32)]
  const int tid = threadIdx.x;
  const int w = tid >> 6, lane = tid & 63;
  const int grp = lane >> 4, l16 = lane & 15;
  const int m0 = blockIdx.y * TM, n0 = blockIdx.x * TN;
  const int rw = (w >> 1) * (TM / 2), cw = (w & 1) * (TN / 2);

  floatx4 acc[FI][FJ] = {};

  const uint16_t* gp[NIT];
  uint16_t* lp[NIT];
#pragma unroll
  for (int i = 0; i < NIT; i++) {
    int c = i * 256 + tid;
    if (c < TM * 4) {
      gp[i] = A + (size_t)(m0 + (c >> 2)) * K + (c & 3) * 8;
      lp[i] = S + c * 8;
    } else {
      int c2 = c - TM * 4;
      gp[i] = B + (size_t)(n0 + (c2 >> 2)) * K + (c2 & 3) * 8;
      lp[i] = S + TM * 32 + c2 * 8;
    }
  }

  const int nt = K / 32;                     // even for all call sites

  auto stage = [&](int t, int buf) {
#pragma unroll
    for (int i = 0; i < NIT; i++) gl2lds16(gp[i] + t * 32, lp[i] + buf * BUFO);
  };
  auto compute = [&](int buf) {
    const uint16_t* Sb = S + buf * BUFO;
    short8 af[FI], bfr[FJ];
#pragma unroll
    for (int i = 0; i < FI; i++)
      af[i] = *(const short8*)(Sb + (rw + i * 16 + l16) * 32 + grp * 8);
#pragma unroll
    for (int j = 0; j < FJ; j++)
      bfr[j] = *(const short8*)(Sb + TM * 32 + (cw + j * 16 + l16) * 32 + grp * 8);
#pragma unroll
    for (int i = 0; i < FI; i++)
#pragma unroll
      for (int j = 0; j < FJ; j++)
        acc[i][j] = __builtin_amdgcn_mfma_f32_16x16x32_bf16(af[i], bfr[j], acc[i][j], 0, 0, 0);
  };

  // prologue: tiles 0,1 in flight; wait tile0 only
  stage(0, 0);
  stage(1, 1);
  __builtin_amdgcn_sched_barrier(0);
  vm_wait<NIT>();
  __builtin_amdgcn_sched_barrier(0);
  __builtin_amdgcn_s_barrier();
  __builtin_amdgcn_sched_barrier(0);

  for (int t = 0;;) {
    compute(0);                              // even tile from buf0
    if (++t == nt) break;
    __builtin_amdgcn_s_barrier();            // all waves done reading buf0
    __builtin_amdgcn_sched_barrier(0);
    if (t + 1 < nt) { stage(t + 1, 0); __builtin_amdgcn_sched_barrier(0); vm_wait<NIT>(); }
    else            vm_wait<0>();
    __builtin_amdgcn_sched_barrier(0);
    __builtin_amdgcn_s_barrier();            // buf1's tile ready
    __builtin_amdgcn_sched_barrier(0);

    compute(1);                              // odd tile from buf1
    if (++t == nt) break;
    __builtin_amdgcn_s_barrier();
    __builtin_amdgcn_sched_barrier(0);
    if (t + 1 < nt) { stage(t + 1, 1); __builtin_amdgcn_sched_barrier(0); vm_wait<NIT>(); }
    else            vm_wait<0>();
    __builtin_amdgcn_sched_barrier(0);
    __builtin_amdgcn_s_barrier();
    __builtin_amdgcn_sched_barrier(0);
  }

  if constexpr (MODE == 2) {
    const int half = N >> 1;
#pragma unroll
    for (int i = 0; i < FI; i++) {
      const int mrow = m0 + rw + i * 16 + grp * 4;
#pragma unroll
      for (int j = 0; j < 2; j++) {
        const int gcol = (n0 >> 1) + (cw >> 1) + j * 16 + l16;
#pragma unroll
        for (int r = 0; r < 4; r++) {
          float a = acc[i][j][r];
          float bv = acc[i][j + 2][r];
          float ex = __builtin_amdgcn_exp2f(-a * 1.4426950408889634f);
          float s = a * __builtin_amdgcn_rcpf(1.0f + ex);
          Cb[(size_t)(mrow + r) * half + gcol] = f2bf(s * bv);
        }
      }
    }
  } else {
#pragma unroll
    for (int i = 0; i < FI; i++) {
#pragma unroll
      for (int j = 0; j < FJ; j++) {
        const int mrow = m0 + rw + i * 16 + grp * 4;
        const int ncol = n0 + cw + j * 16 + l16;
#pragma unroll
        for (int r = 0; r < 4; r++) {
          size_t idx = (size_t)(mrow + r) * N + ncol;
          float v = acc[i][j][r];
          if (MODE == 0) Cb[idx] = f2bf(v);
          else           Cf[idx] = v + Res[idx];
        }
      }
    }
  }
}

// ---------------------------------------------------------------- flash attention
// qkv: [NTOK][3072] bf16 ([3][H][64] per token). out: [NTOK][D] bf16.
// Block = 128 q-rows x one head x one batch; 4 waves, each owns 32 q-rows.
// Grid 512, LDS 54KB. 64-token KV chunks, K/V double-buffered, ONE barrier
// per chunk. Q fragments direct from global. SWAPPED QK^T (S^T = mfma(K,Q)),
// P stored as packed b64 to Ps[q][k]. PAD 76 (not 72!): stride 76 rows =
// 152B = 38 dwords = 6 banks mod 32 -> b128 PV reads conflict-free (r0
// measured 0 conflicts); stride 72 = 4 banks mod 32 -> 8-way alias
// (r9 measured 5.24M conflict cycles = ~8.5us/CU). T5 setprio around MFMA
// clusters. XCD remap: 4 (h,b) pairs/XCD for K/V L2 reuse.
__global__ __launch_bounds__(256, 2) void attn_flash(const uint16_t* __restrict__ qkv,
                                                     uint16_t* __restrict__ outp) {
  const int tid = threadIdx.x;
  const int w = tid >> 6, lane = tid & 63;
  const int grp = lane >> 4, l16 = lane & 15;
  const int lin = blockIdx.x;               // 512 blocks
  const int xcd = lin & 7;
  const int slot = lin >> 3;                // 0..63
  const int pair = xcd * 4 + (slot >> 4);   // 0..31
  const int qc = slot & 15;
  const int h = pair & 15, b = pair >> 4;
  const int q0 = qc * 128;

  __shared__ uint16_t Ks[2][4096];          // 64x64, XOR-swizzled 16B chunks
  __shared__ uint16_t Vt[2][64 * 76];       // V^T [d][t], pad 76
  __shared__ uint16_t Ps[128 * 76];         // P [q][k], pad 76, per-wave 32 rows

  const size_t base = ((size_t)b * LSEQ) * 3072 + (size_t)h * 64;

  // ---- Q fragments straight from global (read once, 128B/lane)
  short8 aq[2][2];
#pragma unroll
  for (int fi = 0; fi < 2; fi++) {
    const uint16_t* qr = qkv + base + (size_t)(q0 + w * 32 + fi * 16 + l16) * 3072;
    aq[fi][0] = *(const short8*)(qr + grp * 8);
    aq[fi][1] = *(const short8*)(qr + 32 + grp * 8);
  }

  // ---- prologue: K0 (swizzled, async), V0 (VALU transpose)
#pragma unroll
  for (int i = 0; i < 2; i++) {
    int c = i * 256 + tid;
    int row = c >> 3, cc = (c & 7) ^ (row & 7);
    gl2lds16(qkv + base + (size_t)row * 3072 + 1024 + cc * 8, Ks[0] + c * 8);
  }
#pragma unroll
  for (int i = 0; i < 2; i++) {
    int c = i * 256 + tid;
    int tt = c & 63, db = c >> 6;
    uint4 vv = *(const uint4*)(qkv + base + (size_t)tt * 3072 + 2048 + db * 8);
    uint32_t uu[4] = {vv.x, vv.y, vv.z, vv.w};
#pragma unroll
    for (int e = 0; e < 4; e++) {
      Vt[0][(db * 8 + e * 2 + 0) * 76 + tt] = (uint16_t)(uu[e] & 0xFFFFu);
      Vt[0][(db * 8 + e * 2 + 1) * 76 + tt] = (uint16_t)(uu[e] >> 16);
    }
  }
  __syncthreads();

  float lsum[2] = {};                       // row-sum for q = fi*16 + l16
  floatx4 o_acc[2][4] = {};
  const float C = 0.125f * 1.4426950408889634f;   // 1/sqrt(64) * log2(e)

  for (int kc = 0; kc < LSEQ / 64; kc++) {
    const int cur = kc & 1, nxt = cur ^ 1;
    const bool pre = (kc + 1 < LSEQ / 64);
    const int t1 = (kc + 1) * 64;
    uint4 vv[2];
    if (pre) {
      // K prefetch: async direct-to-LDS into next buffer
#pragma unroll
      for (int i = 0; i < 2; i++) {
        int c = i * 256 + tid;
        int row = c >> 3, cc = (c & 7) ^ (row & 7);
        gl2lds16(qkv + base + (size_t)(t1 + row) * 3072 + 1024 + cc * 8, Ks[nxt] + c * 8);
      }
      // V prefetch into VGPRs (spilled to LDS after compute)
#pragma unroll
      for (int i = 0; i < 2; i++) {
        int c = i * 256 + tid;
        int tt = c & 63, db = c >> 6;
        vv[i] = *(const uint4*)(qkv + base + (size_t)(t1 + tt) * 3072 + 2048 + db * 8);
      }
    }

    // ---- S^T = K Q^T from Ks[cur] (swapped operands)
    // s_acc[j][fi]: lane holds S[q = fi*16 + l16][k = j*16 + grp*4 + r]
    floatx4 s_acc[4][2] = {};
    __builtin_amdgcn_s_setprio(1);
#pragma unroll
    for (int j = 0; j < 4; j++) {
      const int krow = j * 16 + l16;
#pragma unroll
      for (int kk = 0; kk < 2; kk++) {
        int cc = kk * 4 + grp;
        short8 bk = *(const short8*)(Ks[cur] + (krow * 8 + (cc ^ (krow & 7))) * 8);
#pragma unroll
        for (int fi = 0; fi < 2; fi++)
          s_acc[j][fi] = __builtin_amdgcn_mfma_f32_16x16x32_bf16(bk, aq[fi][kk], s_acc[j][fi], 0, 0, 0);
      }
    }
    __builtin_amdgcn_s_setprio(0);

    // ---- p = 2^(s*C); per-lane row sums; packed b64 stores to Ps[q][k]
#pragma unroll
    for (int j = 0; j < 4; j++)
#pragma unroll
      for (int fi = 0; fi < 2; fi++) {
        float p0 = __builtin_amdgcn_exp2f(s_acc[j][fi][0] * C);
        float p1 = __builtin_amdgcn_exp2f(s_acc[j][fi][1] * C);
        float p2 = __builtin_amdgcn_exp2f(s_acc[j][fi][2] * C);
        float p3 = __builtin_amdgcn_exp2f(s_acc[j][fi][3] * C);
        lsum[fi] += (p0 + p1) + (p2 + p3);
        uint2 pk;
        pk.x = cvt_pk_bf16(p0, p1);
        pk.y = cvt_pk_bf16(p2, p3);
        *(uint2*)(Ps + (w * 32 + fi * 16 + l16) * 76 + j * 16 + grp * 4) = pk;
      }

    // ---- O += P V from Vt[cur] (wave-local Ps rows; same-wave LDS order)
    __builtin_amdgcn_s_setprio(1);
#pragma unroll
    for (int kk = 0; kk < 2; kk++) {
      short8 ap0 = *(const short8*)(Ps + (w * 32 + l16) * 76 + kk * 32 + grp * 8);
      short8 ap1 = *(const short8*)(Ps + (w * 32 + 16 + l16) * 76 + kk * 32 + grp * 8);
#pragma unroll
      for (int jj = 0; jj < 4; jj++) {
        short8 bv = *(const short8*)(Vt[cur] + (jj * 16 + l16) * 76 + kk * 32 + grp * 8);
        o_acc[0][jj] = __builtin_amdgcn_mfma_f32_16x16x32_bf16(ap0, bv, o_acc[0][jj], 0, 0, 0);
        o_acc[1][jj] = __builtin_amdgcn_mfma_f32_16x16x32_bf16(ap1, bv, o_acc[1][jj], 0, 0, 0);
      }
    }
    __builtin_amdgcn_s_setprio(0);

    // spill prefetched V into next buffer
    if (pre) {
#pragma unroll
      for (int i = 0; i < 2; i++) {
        int c = i * 256 + tid;
        int tt = c & 63, db = c >> 6;
        uint32_t uu[4] = {vv[i].x, vv[i].y, vv[i].z, vv[i].w};
#pragma unroll
        for (int e = 0; e < 4; e++) {
          Vt[nxt][(db * 8 + e * 2 + 0) * 76 + tt] = (uint16_t)(uu[e] & 0xFFFFu);
          Vt[nxt][(db * 8 + e * 2 + 1) * 76 + tt] = (uint16_t)(uu[e] >> 16);
        }
      }
    }
    __syncthreads();
  }

  // epilogue: reduce row sums across grp axis, redistribute, normalize, store
#pragma unroll
  for (int fi = 0; fi < 2; fi++) {
    lsum[fi] += __shfl_xor(lsum[fi], 16, 64);
    lsum[fi] += __shfl_xor(lsum[fi], 32, 64);
  }
  // lane (grp,l16) needs lsum for q = fi*16 + grp*4 + r -> from lane grp*4+r
  float lsr[2][4];
#pragma unroll
  for (int fi = 0; fi < 2; fi++)
#pragma unroll
    for (int r = 0; r < 4; r++)
      lsr[fi][r] = __shfl(lsum[fi], grp * 4 + r, 64);
#pragma unroll
  for (int fi = 0; fi < 2; fi++)
#pragma unroll
    for (int jj = 0; jj < 4; jj++)
#pragma unroll
      for (int r = 0; r < 4; r++) {
        int row = b * LSEQ + q0 + w * 32 + fi * 16 + grp * 4 + r;
        float o = o_acc[fi][jj][r] * __builtin_amdgcn_rcpf(lsr[fi][r]);
        outp[(size_t)row * DMODEL + h * 64 + jj * 16 + l16] = f2bf(o);
      }
}

// ---------------------------------------------------------------- launch
extern "C" void kernel_launch(void* const* d_in, const int* in_sizes, int n_in,
                              void* d_out, int out_size, void* d_ws, size_t ws_size,
                              hipStream_t stream) {
  const float* x    = (const float*)d_in[0];
  const float* wqkv = (const float*)d_in[1];
  const float* wo   = (const float*)d_in[2];
  const float* n1w  = (const float*)d_in[3];
  const float* n2w  = (const float*)d_in[4];
  const float* w1   = (const float*)d_in[5];
  const float* w2   = (const float*)d_in[6];
  const float* w3   = (const float*)d_in[7];
  float* out = (float*)d_out;

  char* p = (char*)d_ws;
  uint16_t* wall  = (uint16_t*)p; p += (size_t)9728 * 1024 * 2;  // wqkv|wo|w13
  uint16_t* wqkvb = wall;
  uint16_t* wob   = wall + (size_t)3072 * 1024;
  uint16_t* w13b  = wall + (size_t)4096 * 1024;
  uint16_t* w2b   = (uint16_t*)p; p += (size_t)1024 * FFP * 2;
  uint16_t* h1    = (uint16_t*)p; p += (size_t)NTOK * DMODEL * 2;
  uint16_t* qkvb  = (uint16_t*)p; p += (size_t)NTOK * 3072 * 2;
  uint16_t* attno = (uint16_t*)p; p += (size_t)NTOK * DMODEL * 2;
  float*    x1    = (float*)p;    p += (size_t)NTOK * DMODEL * 4;
  uint16_t* h2    = (uint16_t*)p; p += (size_t)NTOK * DMODEL * 2;
  uint16_t* gbuf  = (uint16_t*)p; p += (size_t)NTOK * FFP * 2;

  cvt_all_k<<<9728, 256, 0, stream>>>(wqkv, wo, w1, w3, wall);
  cvt_pad_k<<<(1024 * (FFP / 4)) / 256, 256, 0, stream>>>(w2, w2b, 1024, FFR, FFP);

  rmsnorm_k<<<NTOK, 256, 0, stream>>>(x, n1w, h1);
  gemm_bt<0, 128, 128><<<dim3(3072 / 128, NTOK / 128), 256, 0, stream>>>(
      h1, wqkvb, qkvb, nullptr, nullptr, NTOK, 3072, 1024);
  attn_flash<<<512, 256, 0, stream>>>(qkvb, attno);
  gemm_bt<1, 128, 64><<<dim3(1024 / 64, NTOK / 128), 256, 0, stream>>>(
      attno, wob, nullptr, x1, x, NTOK, 1024, 1024);
  rmsnorm_k<<<NTOK, 256, 0, stream>>>(x1, n2w, h2);
  gemm_bt<2, 128, 128><<<dim3(FF2 / 128, NTOK / 128), 256, 0, stream>>>(
      h2, w13b, gbuf, nullptr, nullptr, NTOK, FF2, 1024);
  gemm_bt<1, 128, 64><<<dim3(1024 / 64, NTOK / 128), 256, 0, stream>>>(
      gbuf, w2b, nullptr, out, x1, NTOK, 1024, FFP);
}

// Round 11
// 337.936 us; speedup vs baseline: 1.0246x; 1.0246x over previous
//
#include <hip/hip_runtime.h>
#include <stdint.h>

// Transformer block: x + attn(rmsnorm(x)) then + swiglu(rmsnorm(.))
// bf16 MFMA (16x16x32), fp32 accumulate, fp32 residuals.
// B=2, L=2048, D=1024, H=16, DK=64, FF=2730 (padded to 2816).

#define LSEQ   2048
#define DMODEL 1024
#define NHEAD  16
#define NTOK   4096
#define FFR    2730
#define FFP    2816
#define FF2    5632          // w1|w3 fused N (interleaved in 32-row units)

typedef short  short8  __attribute__((ext_vector_type(8)));
typedef float  floatx4 __attribute__((ext_vector_type(4)));

__device__ __forceinline__ uint16_t f2bf(float f) {
  uint32_t u = __builtin_bit_cast(uint32_t, f);
  u += 0x7FFFu + ((u >> 16) & 1u);          // RNE
  return (uint16_t)(u >> 16);
}
// v_cvt_pk_bf16_f32: low=a, high=b. Proven bit-identical to explicit RNE pack
// (rounds 1/2 produced identical outputs with cvt_pk vs explicit f2bf pack).
__device__ __forceinline__ uint32_t cvt_pk_bf16(float a, float b) {
  uint32_t d;
  asm("v_cvt_pk_bf16_f32 %0, %1, %2" : "=v"(d) : "v"(a), "v"(b));
  return d;
}
__device__ __forceinline__ void gl2lds16(const void* g, void* l) {
  __builtin_amdgcn_global_load_lds(
      (const __attribute__((address_space(1))) unsigned int*)g,
      (__attribute__((address_space(3))) unsigned int*)l, 16, 0, 0);
}
// counted VMEM wait (T4). Literal-only asm string, if constexpr dispatch.
template <int N>
__device__ __forceinline__ void vm_wait() {
  if constexpr (N == 0)      asm volatile("s_waitcnt vmcnt(0)" ::: "memory");
  else if constexpr (N == 3) asm volatile("s_waitcnt vmcnt(3)" ::: "memory");
  else if constexpr (N == 4) asm volatile("s_waitcnt vmcnt(4)" ::: "memory");
}

// ------------------------------------------------ fused weight convert
// dst rows: [0,3072) wqkv | [3072,4096) wo |
// [4096,9728) w13 interleaved: unit u (64 rows) = [w1 rows u*32..+31 | w3 rows u*32..+31]
__global__ __launch_bounds__(256) void cvt_all_k(const float* __restrict__ wqkv,
                                                 const float* __restrict__ wo,
                                                 const float* __restrict__ w1,
                                                 const float* __restrict__ w3,
                                                 uint16_t* __restrict__ dst) {
  int g = blockIdx.x;                 // one row (1024 cols) per block
  int c = threadIdx.x * 4;
  const float* src = nullptr;
  if (g < 3072)       src = wqkv + (size_t)g * 1024;
  else if (g < 4096)  src = wo + (size_t)(g - 3072) * 1024;
  else {
    int r = g - 4096;                 // 0..5631
    int u = r >> 6, wi = r & 63;
    int srow = u * 32 + (wi & 31);
    if (srow < FFR) src = ((wi < 32) ? w1 : w3) + (size_t)srow * 1024;
  }
  float4 v = src ? *(const float4*)(src + c) : float4{0, 0, 0, 0};
  uint64_t pack =  (uint64_t)f2bf(v.x)        | ((uint64_t)f2bf(v.y) << 16)
                | ((uint64_t)f2bf(v.z) << 32) | ((uint64_t)f2bf(v.w) << 48);
  *(uint64_t*)(dst + (size_t)g * 1024 + c) = pack;
}

// w2 needs column padding 2730->2816; 4 cols/thread, uint64 store.
__global__ __launch_bounds__(256) void cvt_pad_k(const float* __restrict__ src,
                                                 uint16_t* __restrict__ dst,
                                                 int rows, int cols, int cols_p) {
  long idx = (long)blockIdx.x * 256 + threadIdx.x;   // one per 4 cols
  int c4 = cols_p >> 2;
  if (idx >= (long)rows * c4) return;
  int r = (int)(idx / c4);
  int c = (int)(idx % c4) * 4;
  uint64_t pack;
  if (c + 3 < cols) {
    const float* sp = src + (size_t)r * cols + c;
    float2 a = *(const float2*)sp;
    float2 b2 = *(const float2*)(sp + 2);
    pack =  (uint64_t)f2bf(a.x)        | ((uint64_t)f2bf(a.y) << 16)
         | ((uint64_t)f2bf(b2.x) << 32) | ((uint64_t)f2bf(b2.y) << 48);
  } else {
    pack = 0;
    for (int e = 0; e < 4; e++) {
      float v = (c + e < cols) ? src[(size_t)r * cols + c + e] : 0.0f;
      pack |= (uint64_t)f2bf(v) << (16 * e);
    }
  }
  *(uint64_t*)(dst + (size_t)r * cols_p + c) = pack;
}

// ---------------------------------------------------------------- rmsnorm
__global__ __launch_bounds__(256) void rmsnorm_k(const float* __restrict__ x,
                                                 const float* __restrict__ wgt,
                                                 uint16_t* __restrict__ out) {
  const int row = blockIdx.x;
  const int c = threadIdx.x * 4;
  const float* xr = x + (size_t)row * DMODEL;
  float4 v = *(const float4*)(xr + c);
  float ss = v.x * v.x + v.y * v.y + v.z * v.z + v.w * v.w;
#pragma unroll
  for (int off = 32; off >= 1; off >>= 1) ss += __shfl_down(ss, off, 64);
  __shared__ float red[4];
  if ((threadIdx.x & 63) == 0) red[threadIdx.x >> 6] = ss;
  __syncthreads();
  float tot = red[0] + red[1] + red[2] + red[3];
  float scale = rsqrtf(tot * (1.0f / DMODEL) + 1e-6f);
  float4 wv = *(const float4*)(wgt + c);
  uint64_t pack =  (uint64_t)f2bf(v.x * scale * wv.x)
                | ((uint64_t)f2bf(v.y * scale * wv.y) << 16)
                | ((uint64_t)f2bf(v.z * scale * wv.z) << 32)
                | ((uint64_t)f2bf(v.w * scale * wv.w) << 48);
  *(uint64_t*)(out + (size_t)row * DMODEL + c) = pack;
}

// ---------------------------------------------------------------- GEMM
// C[M,N] = A[M,K](bf16,row) @ B[N,K](bf16,row)^T ; tile TM x TN, 4 waves (2x2).
// MODE 0: bf16 store. MODE 1: fp32 Cf = acc + Res.
// MODE 2 (TN=128): B rows interleaved w1/w3 in 32-row units; epilogue computes
//   silu(a)*b in-register, writes bf16 to Cb with row stride N/2.
// T4 pipeline (counted vmcnt, m218 mechanism): double-buffered LDS, raw
// s_barrier (no vmcnt(0) drain in the loop). Verified r9: 368.6->341.1us.
template <int MODE, int TM, int TN>
__global__ __launch_bounds__(256) void gemm_bt(const uint16_t* __restrict__ A,
                                               const uint16_t* __restrict__ B,
                                               uint16_t* __restrict__ Cb,
                                               float* __restrict__ Cf,
                                               const float* __restrict__ Res,
                                               int M, int N, int K) {
  constexpr int FI = TM / 32, FJ = TN / 32;
  constexpr int NIT = (TM + TN) / 64;
  constexpr int BUFO = (TM + TN) * 32;       // uint16 elems per buffer
  __shared__ uint16_t S[2 * BUFO];           // [buf][A(TM*32) | B(TN*32)]
  const int tid = threadIdx.x;
  const int w = tid >> 6, lane = tid & 63;
  const int grp = lane >> 4, l16 = lane & 15;
  const int m0 = blockIdx.y * TM, n0 = blockIdx.x * TN;
  const int rw = (w >> 1) * (TM / 2), cw = (w & 1) * (TN / 2);

  floatx4 acc[FI][FJ] = {};

  const uint16_t* gp[NIT];
  uint16_t* lp[NIT];
#pragma unroll
  for (int i = 0; i < NIT; i++) {
    int c = i * 256 + tid;
    if (c < TM * 4) {
      gp[i] = A + (size_t)(m0 + (c >> 2)) * K + (c & 3) * 8;
      lp[i] = S + c * 8;
    } else {
      int c2 = c - TM * 4;
      gp[i] = B + (size_t)(n0 + (c2 >> 2)) * K + (c2 & 3) * 8;
      lp[i] = S + TM * 32 + c2 * 8;
    }
  }

  const int nt = K / 32;                     // even for all call sites

  auto stage = [&](int t, int buf) {
#pragma unroll
    for (int i = 0; i < NIT; i++) gl2lds16(gp[i] + t * 32, lp[i] + buf * BUFO);
  };
  auto compute = [&](int buf) {
    const uint16_t* Sb = S + buf * BUFO;
    short8 af[FI], bfr[FJ];
#pragma unroll
    for (int i = 0; i < FI; i++)
      af[i] = *(const short8*)(Sb + (rw + i * 16 + l16) * 32 + grp * 8);
#pragma unroll
    for (int j = 0; j < FJ; j++)
      bfr[j] = *(const short8*)(Sb + TM * 32 + (cw + j * 16 + l16) * 32 + grp * 8);
#pragma unroll
    for (int i = 0; i < FI; i++)
#pragma unroll
      for (int j = 0; j < FJ; j++)
        acc[i][j] = __builtin_amdgcn_mfma_f32_16x16x32_bf16(af[i], bfr[j], acc[i][j], 0, 0, 0);
  };

  // prologue: tiles 0,1 in flight; wait tile0 only
  stage(0, 0);
  stage(1, 1);
  __builtin_amdgcn_sched_barrier(0);
  vm_wait<NIT>();
  __builtin_amdgcn_sched_barrier(0);
  __builtin_amdgcn_s_barrier();
  __builtin_amdgcn_sched_barrier(0);

  for (int t = 0;;) {
    compute(0);                              // even tile from buf0
    if (++t == nt) break;
    __builtin_amdgcn_s_barrier();            // all waves done reading buf0
    __builtin_amdgcn_sched_barrier(0);
    if (t + 1 < nt) { stage(t + 1, 0); __builtin_amdgcn_sched_barrier(0); vm_wait<NIT>(); }
    else            vm_wait<0>();
    __builtin_amdgcn_sched_barrier(0);
    __builtin_amdgcn_s_barrier();            // buf1's tile ready
    __builtin_amdgcn_sched_barrier(0);

    compute(1);                              // odd tile from buf1
    if (++t == nt) break;
    __builtin_amdgcn_s_barrier();
    __builtin_amdgcn_sched_barrier(0);
    if (t + 1 < nt) { stage(t + 1, 1); __builtin_amdgcn_sched_barrier(0); vm_wait<NIT>(); }
    else            vm_wait<0>();
    __builtin_amdgcn_sched_barrier(0);
    __builtin_amdgcn_s_barrier();
    __builtin_amdgcn_sched_barrier(0);
  }

  if constexpr (MODE == 2) {
    const int half = N >> 1;
#pragma unroll
    for (int i = 0; i < FI; i++) {
      const int mrow = m0 + rw + i * 16 + grp * 4;
#pragma unroll
      for (int j = 0; j < 2; j++) {
        const int gcol = (n0 >> 1) + (cw >> 1) + j * 16 + l16;
#pragma unroll
        for (int r = 0; r < 4; r++) {
          float a = acc[i][j][r];
          float bv = acc[i][j + 2][r];
          float ex = __builtin_amdgcn_exp2f(-a * 1.4426950408889634f);
          float s = a * __builtin_amdgcn_rcpf(1.0f + ex);
          Cb[(size_t)(mrow + r) * half + gcol] = f2bf(s * bv);
        }
      }
    }
  } else {
#pragma unroll
    for (int i = 0; i < FI; i++) {
#pragma unroll
      for (int j = 0; j < FJ; j++) {
        const int mrow = m0 + rw + i * 16 + grp * 4;
        const int ncol = n0 + cw + j * 16 + l16;
#pragma unroll
        for (int r = 0; r < 4; r++) {
          size_t idx = (size_t)(mrow + r) * N + ncol;
          float v = acc[i][j][r];
          if (MODE == 0) Cb[idx] = f2bf(v);
          else           Cf[idx] = v + Res[idx];
        }
      }
    }
  }
}

// ---------------------------------------------------------------- flash attention
// qkv: [NTOK][3072] bf16 ([3][H][64] per token). out: [NTOK][D] bf16.
// Block = 128 q-rows x one head x one batch; 8 WAVES (512 thr), each owns
// 16 q-rows. Same per-block totals/barriers as the 4-wave version but
// 2x waves/SIMD (4) for latency hiding (r10 was latency-bound: MfmaUtil 20%,
// VALUBusy 33%, occ 2 waves/SIMD). Grid 512, LDS 54KB -> 2 blocks/CU =
// 16 waves/CU. 64-token KV chunks, K/V double-buffered, ONE barrier/chunk.
// Q direct from global. SWAPPED QK^T (S^T = mfma(K,Q)); P packed b64 to
// Ps[q][k]; pad 76 (conflict-free, r10 measured 0). T5 setprio around MFMA.
// XCD remap: 4 (h,b) pairs/XCD for K/V L2 reuse.
__global__ __launch_bounds__(512, 2) void attn_flash(const uint16_t* __restrict__ qkv,
                                                     uint16_t* __restrict__ outp) {
  const int tid = threadIdx.x;
  const int w = tid >> 6, lane = tid & 63;
  const int grp = lane >> 4, l16 = lane & 15;
  const int lin = blockIdx.x;               // 512 blocks
  const int xcd = lin & 7;
  const int slot = lin >> 3;                // 0..63
  const int pair = xcd * 4 + (slot >> 4);   // 0..31
  const int qc = slot & 15;
  const int h = pair & 15, b = pair >> 4;
  const int q0 = qc * 128;

  __shared__ uint16_t Ks[2][4096];          // 64x64, XOR-swizzled 16B chunks
  __shared__ uint16_t Vt[2][64 * 76];       // V^T [d][t], pad 76
  __shared__ uint16_t Ps[128 * 76];         // P [q][k], pad 76, 16 rows/wave

  const size_t base = ((size_t)b * LSEQ) * 3072 + (size_t)h * 64;

  // ---- Q fragments straight from global (read once, 64B/lane)
  short8 aq[2];
  {
    const uint16_t* qr = qkv + base + (size_t)(q0 + w * 16 + l16) * 3072;
    aq[0] = *(const short8*)(qr + grp * 8);
    aq[1] = *(const short8*)(qr + 32 + grp * 8);
  }

  // ---- prologue: K0 (swizzled, async), V0 (VALU transpose)
  {
    int c = tid;
    int row = c >> 3, cc = (c & 7) ^ (row & 7);
    gl2lds16(qkv + base + (size_t)row * 3072 + 1024 + cc * 8, Ks[0] + c * 8);
  }
  {
    int c = tid;
    int tt = c & 63, db = c >> 6;
    uint4 vv = *(const uint4*)(qkv + base + (size_t)tt * 3072 + 2048 + db * 8);
    uint32_t uu[4] = {vv.x, vv.y, vv.z, vv.w};
#pragma unroll
    for (int e = 0; e < 4; e++) {
      Vt[0][(db * 8 + e * 2 + 0) * 76 + tt] = (uint16_t)(uu[e] & 0xFFFFu);
      Vt[0][(db * 8 + e * 2 + 1) * 76 + tt] = (uint16_t)(uu[e] >> 16);
    }
  }
  __syncthreads();

  float lsum = 0.0f;                        // row-sum for q = w*16 + l16
  floatx4 o_acc[4] = {};
  const float C = 0.125f * 1.4426950408889634f;   // 1/sqrt(64) * log2(e)

  for (int kc = 0; kc < LSEQ / 64; kc++) {
    const int cur = kc & 1, nxt = cur ^ 1;
    const bool pre = (kc + 1 < LSEQ / 64);
    const int t1 = (kc + 1) * 64;
    uint4 vv;
    if (pre) {
      // K prefetch: async direct-to-LDS into next buffer
      int c = tid;
      int row = c >> 3, cc = (c & 7) ^ (row & 7);
      gl2lds16(qkv + base + (size_t)(t1 + row) * 3072 + 1024 + cc * 8, Ks[nxt] + c * 8);
      // V prefetch into VGPRs (spilled to LDS after compute)
      int tt = c & 63, db = c >> 6;
      vv = *(const uint4*)(qkv + base + (size_t)(t1 + tt) * 3072 + 2048 + db * 8);
    }

    // ---- S^T = K Q^T from Ks[cur] (swapped operands)
    // s_acc[j]: lane holds S[q = w*16 + l16][k = j*16 + grp*4 + r]
    floatx4 s_acc[4] = {};
    __builtin_amdgcn_s_setprio(1);
#pragma unroll
    for (int j = 0; j < 4; j++) {
      const int krow = j * 16 + l16;
#pragma unroll
      for (int kk = 0; kk < 2; kk++) {
        int cc = kk * 4 + grp;
        short8 bk = *(const short8*)(Ks[cur] + (krow * 8 + (cc ^ (krow & 7))) * 8);
        s_acc[j] = __builtin_amdgcn_mfma_f32_16x16x32_bf16(bk, aq[kk], s_acc[j], 0, 0, 0);
      }
    }
    __builtin_amdgcn_s_setprio(0);

    // ---- p = 2^(s*C); per-lane row sums; packed b64 stores to Ps[q][k]
#pragma unroll
    for (int j = 0; j < 4; j++) {
      float p0 = __builtin_amdgcn_exp2f(s_acc[j][0] * C);
      float p1 = __builtin_amdgcn_exp2f(s_acc[j][1] * C);
      float p2 = __builtin_amdgcn_exp2f(s_acc[j][2] * C);
      float p3 = __builtin_amdgcn_exp2f(s_acc[j][3] * C);
      lsum += (p0 + p1) + (p2 + p3);
      uint2 pk;
      pk.x = cvt_pk_bf16(p0, p1);
      pk.y = cvt_pk_bf16(p2, p3);
      *(uint2*)(Ps + (w * 16 + l16) * 76 + j * 16 + grp * 4) = pk;
    }

    // ---- O += P V from Vt[cur] (wave-local Ps rows; same-wave LDS order)
    __builtin_amdgcn_s_setprio(1);
#pragma unroll
    for (int kk = 0; kk < 2; kk++) {
      short8 ap = *(const short8*)(Ps + (w * 16 + l16) * 76 + kk * 32 + grp * 8);
#pragma unroll
      for (int jj = 0; jj < 4; jj++) {
        short8 bv = *(const short8*)(Vt[cur] + (jj * 16 + l16) * 76 + kk * 32 + grp * 8);
        o_acc[jj] = __builtin_amdgcn_mfma_f32_16x16x32_bf16(ap, bv, o_acc[jj], 0, 0, 0);
      }
    }
    __builtin_amdgcn_s_setprio(0);

    // spill prefetched V into next buffer
    if (pre) {
      int c = tid;
      int tt = c & 63, db = c >> 6;
      uint32_t uu[4] = {vv.x, vv.y, vv.z, vv.w};
#pragma unroll
      for (int e = 0; e < 4; e++) {
        Vt[nxt][(db * 8 + e * 2 + 0) * 76 + tt] = (uint16_t)(uu[e] & 0xFFFFu);
        Vt[nxt][(db * 8 + e * 2 + 1) * 76 + tt] = (uint16_t)(uu[e] >> 16);
      }
    }
    __syncthreads();
  }

  // epilogue: reduce row sums across grp axis, redistribute, normalize, store
  lsum += __shfl_xor(lsum, 16, 64);
  lsum += __shfl_xor(lsum, 32, 64);
  // lane (grp,l16) needs lsum for q = w*16 + grp*4 + r -> from lane grp*4+r
  float lsr[4];
#pragma unroll
  for (int r = 0; r < 4; r++) lsr[r] = __shfl(lsum, grp * 4 + r, 64);
#pragma unroll
  for (int jj = 0; jj < 4; jj++)
#pragma unroll
    for (int r = 0; r < 4; r++) {
      int row = b * LSEQ + q0 + w * 16 + grp * 4 + r;
      float o = o_acc[jj][r] * __builtin_amdgcn_rcpf(lsr[r]);
      outp[(size_t)row * DMODEL + h * 64 + jj * 16 + l16] = f2bf(o);
    }
}

// ---------------------------------------------------------------- launch
extern "C" void kernel_launch(void* const* d_in, const int* in_sizes, int n_in,
                              void* d_out, int out_size, void* d_ws, size_t ws_size,
                              hipStream_t stream) {
  const float* x    = (const float*)d_in[0];
  const float* wqkv = (const float*)d_in[1];
  const float* wo   = (const float*)d_in[2];
  const float* n1w  = (const float*)d_in[3];
  const float* n2w  = (const float*)d_in[4];
  const float* w1   = (const float*)d_in[5];
  const float* w2   = (const float*)d_in[6];
  const float* w3   = (const float*)d_in[7];
  float* out = (float*)d_out;

  char* p = (char*)d_ws;
  uint16_t* wall  = (uint16_t*)p; p += (size_t)9728 * 1024 * 2;  // wqkv|wo|w13
  uint16_t* wqkvb = wall;
  uint16_t* wob   = wall + (size_t)3072 * 1024;
  uint16_t* w13b  = wall + (size_t)4096 * 1024;
  uint16_t* w2b   = (uint16_t*)p; p += (size_t)1024 * FFP * 2;
  uint16_t* h1    = (uint16_t*)p; p += (size_t)NTOK * DMODEL * 2;
  uint16_t* qkvb  = (uint16_t*)p; p += (size_t)NTOK * 3072 * 2;
  uint16_t* attno = (uint16_t*)p; p += (size_t)NTOK * DMODEL * 2;
  float*    x1    = (float*)p;    p += (size_t)NTOK * DMODEL * 4;
  uint16_t* h2    = (uint16_t*)p; p += (size_t)NTOK * DMODEL * 2;
  uint16_t* gbuf  = (uint16_t*)p; p += (size_t)NTOK * FFP * 2;

  cvt_all_k<<<9728, 256, 0, stream>>>(wqkv, wo, w1, w3, wall);
  cvt_pad_k<<<(1024 * (FFP / 4)) / 256, 256, 0, stream>>>(w2, w2b, 1024, FFR, FFP);

  rmsnorm_k<<<NTOK, 256, 0, stream>>>(x, n1w, h1);
  gemm_bt<0, 128, 128><<<dim3(3072 / 128, NTOK / 128), 256, 0, stream>>>(
      h1, wqkvb, qkvb, nullptr, nullptr, NTOK, 3072, 1024);
  attn_flash<<<512, 512, 0, stream>>>(qkvb, attno);
  gemm_bt<1, 128, 64><<<dim3(1024 / 64, NTOK / 128), 256, 0, stream>>>(
      attno, wob, nullptr, x1, x, NTOK, 1024, 1024);
  rmsnorm_k<<<NTOK, 256, 0, stream>>>(x1, n2w, h2);
  gemm_bt<2, 128, 128><<<dim3(FF2 / 128, NTOK / 128), 256, 0, stream>>>(
      h2, w13b, gbuf, nullptr, nullptr, NTOK, FF2, 1024);
  gemm_bt<1, 128, 64><<<dim3(1024 / 64, NTOK / 128), 256, 0, stream>>>(
      gbuf, w2b, nullptr, out, x1, NTOK, 1024, FFP);
}

// Round 13
// 335.166 us; speedup vs baseline: 1.0331x; 1.0083x over previous
//
#include <hip/hip_runtime.h>
#include <stdint.h>

// Transformer block: x + attn(rmsnorm(x)) then + swiglu(rmsnorm(.))
// bf16 MFMA (16x16x32), fp32 accumulate, fp32 residuals.
// B=2, L=2048, D=1024, H=16, DK=64, FF=2730 (padded to 2816).

#define LSEQ   2048
#define DMODEL 1024
#define NHEAD  16
#define NTOK   4096
#define FFR    2730
#define FFP    2816
#define FF2    5632          // w1|w3 fused N (interleaved in 32-row units)

typedef short  short8  __attribute__((ext_vector_type(8)));
typedef float  floatx4 __attribute__((ext_vector_type(4)));

__device__ __forceinline__ uint16_t f2bf(float f) {
  uint32_t u = __builtin_bit_cast(uint32_t, f);
  u += 0x7FFFu + ((u >> 16) & 1u);          // RNE
  return (uint16_t)(u >> 16);
}
// v_cvt_pk_bf16_f32: low=a, high=b. Proven bit-identical to explicit RNE pack.
__device__ __forceinline__ uint32_t cvt_pk_bf16(float a, float b) {
  uint32_t d;
  asm("v_cvt_pk_bf16_f32 %0, %1, %2" : "=v"(d) : "v"(a), "v"(b));
  return d;
}
__device__ __forceinline__ void gl2lds16(const void* g, void* l) {
  __builtin_amdgcn_global_load_lds(
      (const __attribute__((address_space(1))) unsigned int*)g,
      (__attribute__((address_space(3))) unsigned int*)l, 16, 0, 0);
}
// counted VMEM wait (T4). Literal-only asm string, if constexpr dispatch.
template <int N>
__device__ __forceinline__ void vm_wait() {
  if constexpr (N == 0)      asm volatile("s_waitcnt vmcnt(0)" ::: "memory");
  else if constexpr (N == 3) asm volatile("s_waitcnt vmcnt(3)" ::: "memory");
  else if constexpr (N == 4) asm volatile("s_waitcnt vmcnt(4)" ::: "memory");
  else if constexpr (N == 6) asm volatile("s_waitcnt vmcnt(6)" ::: "memory");
  else if constexpr (N == 8) asm volatile("s_waitcnt vmcnt(8)" ::: "memory");
}

// ------------------------------------------------ fused weight convert
// dst rows: [0,3072) wqkv | [3072,4096) wo |
// [4096,9728) w13 interleaved: unit u (64 rows) = [w1 rows u*32..+31 | w3 rows u*32..+31]
__global__ __launch_bounds__(256) void cvt_all_k(const float* __restrict__ wqkv,
                                                 const float* __restrict__ wo,
                                                 const float* __restrict__ w1,
                                                 const float* __restrict__ w3,
                                                 uint16_t* __restrict__ dst) {
  int g = blockIdx.x;                 // one row (1024 cols) per block
  int c = threadIdx.x * 4;
  const float* src = nullptr;
  if (g < 3072)       src = wqkv + (size_t)g * 1024;
  else if (g < 4096)  src = wo + (size_t)(g - 3072) * 1024;
  else {
    int r = g - 4096;                 // 0..5631
    int u = r >> 6, wi = r & 63;
    int srow = u * 32 + (wi & 31);
    if (srow < FFR) src = ((wi < 32) ? w1 : w3) + (size_t)srow * 1024;
  }
  float4 v = src ? *(const float4*)(src + c) : float4{0, 0, 0, 0};
  uint64_t pack =  (uint64_t)f2bf(v.x)        | ((uint64_t)f2bf(v.y) << 16)
                | ((uint64_t)f2bf(v.z) << 32) | ((uint64_t)f2bf(v.w) << 48);
  *(uint64_t*)(dst + (size_t)g * 1024 + c) = pack;
}

// w2 needs column padding 2730->2816; 4 cols/thread, uint64 store.
__global__ __launch_bounds__(256) void cvt_pad_k(const float* __restrict__ src,
                                                 uint16_t* __restrict__ dst,
                                                 int rows, int cols, int cols_p) {
  long idx = (long)blockIdx.x * 256 + threadIdx.x;   // one per 4 cols
  int c4 = cols_p >> 2;
  if (idx >= (long)rows * c4) return;
  int r = (int)(idx / c4);
  int c = (int)(idx % c4) * 4;
  uint64_t pack;
  if (c + 3 < cols) {
    const float* sp = src + (size_t)r * cols + c;
    float2 a = *(const float2*)sp;
    float2 b2 = *(const float2*)(sp + 2);
    pack =  (uint64_t)f2bf(a.x)        | ((uint64_t)f2bf(a.y) << 16)
         | ((uint64_t)f2bf(b2.x) << 32) | ((uint64_t)f2bf(b2.y) << 48);
  } else {
    pack = 0;
    for (int e = 0; e < 4; e++) {
      float v = (c + e < cols) ? src[(size_t)r * cols + c + e] : 0.0f;
      pack |= (uint64_t)f2bf(v) << (16 * e);
    }
  }
  *(uint64_t*)(dst + (size_t)r * cols_p + c) = pack;
}

// ---------------------------------------------------------------- rmsnorm
__global__ __launch_bounds__(256) void rmsnorm_k(const float* __restrict__ x,
                                                 const float* __restrict__ wgt,
                                                 uint16_t* __restrict__ out) {
  const int row = blockIdx.x;
  const int c = threadIdx.x * 4;
  const float* xr = x + (size_t)row * DMODEL;
  float4 v = *(const float4*)(xr + c);
  float ss = v.x * v.x + v.y * v.y + v.z * v.z + v.w * v.w;
#pragma unroll
  for (int off = 32; off >= 1; off >>= 1) ss += __shfl_down(ss, off, 64);
  __shared__ float red[4];
  if ((threadIdx.x & 63) == 0) red[threadIdx.x >> 6] = ss;
  __syncthreads();
  float tot = red[0] + red[1] + red[2] + red[3];
  float scale = rsqrtf(tot * (1.0f / DMODEL) + 1e-6f);
  float4 wv = *(const float4*)(wgt + c);
  uint64_t pack =  (uint64_t)f2bf(v.x * scale * wv.x)
                | ((uint64_t)f2bf(v.y * scale * wv.y) << 16)
                | ((uint64_t)f2bf(v.z * scale * wv.z) << 32)
                | ((uint64_t)f2bf(v.w * scale * wv.w) << 48);
  *(uint64_t*)(out + (size_t)row * DMODEL + c) = pack;
}

// ---------------------------------------------------------------- GEMM
// C[M,N] = A[M,K](bf16,row) @ B[N,K](bf16,row)^T ; tile TM x TN, 4 waves (2x2).
// MODE 0: bf16 store. MODE 1: fp32 Cf = acc + Res. MODE 2: fused swiglu.
// T4 pipeline DEPTH 3 (counted vmcnt): triple-buffered LDS, raw s_barrier.
// Invariant: before compute(tile t), tiles t..t+2 staged (if exist), t's
// loads retired. After compute(t)+barrier: stage tile t+3 into t's buffer,
// then wait so that tile t+1 is retired: outstanding = {t+1,t+2,t+3} ->
// vmcnt(2*NIT); tails: only {t+1,t+2} -> NIT; only {t+1} -> 0.
// (r12 FAILED: staged t+2-as-t+1 off-by-one -> tile dup + tile skip.)
// LDS chunk XOR swizzle (r11: 5.77M conflict cycles): chunk ch of row r
// sources global chunk ch^((r>>1)&3) (LDS dest linear, m173); reads apply
// the same XOR -> ds_read_b128 2-way max (free, m136). Pure permutation.
template <int MODE, int TM, int TN>
__global__ __launch_bounds__(256) void gemm_bt(const uint16_t* __restrict__ A,
                                               const uint16_t* __restrict__ B,
                                               uint16_t* __restrict__ Cb,
                                               float* __restrict__ Cf,
                                               const float* __restrict__ Res,
                                               int M, int N, int K) {
  constexpr int FI = TM / 32, FJ = TN / 32;
  constexpr int NIT = (TM + TN) / 64;
  constexpr int BUFO = (TM + TN) * 32;       // uint16 elems per buffer
  __shared__ uint16_t S[3 * BUFO];           // [buf][A(TM*32) | B(TN*32)]
  const int tid = threadIdx.x;
  const int w = tid >> 6, lane = tid & 63;
  const int grp = lane >> 4, l16 = lane & 15;
  const int m0 = blockIdx.y * TM, n0 = blockIdx.x * TN;
  const int rw = (w >> 1) * (TM / 2), cw = (w & 1) * (TN / 2);

  floatx4 acc[FI][FJ] = {};

  const uint16_t* gp[NIT];
  uint16_t* lp[NIT];
#pragma unroll
  for (int i = 0; i < NIT; i++) {
    int c = i * 256 + tid;
    if (c < TM * 4) {
      int row = c >> 2, ch = c & 3;
      gp[i] = A + (size_t)(m0 + row) * K + (ch ^ ((row >> 1) & 3)) * 8;
      lp[i] = S + c * 8;
    } else {
      int c2 = c - TM * 4;
      int row = c2 >> 2, ch = c2 & 3;
      gp[i] = B + (size_t)(n0 + row) * K + (ch ^ ((row >> 1) & 3)) * 8;
      lp[i] = S + TM * 32 + c2 * 8;
    }
  }

  const int nt = K / 32;                     // >= 3 for all call sites

  auto stage = [&](int t, int buf) {
#pragma unroll
    for (int i = 0; i < NIT; i++) gl2lds16(gp[i] + t * 32, lp[i] + buf * BUFO);
  };
  auto compute = [&](int buf) {
    const uint16_t* Sb = S + buf * BUFO;
    short8 af[FI], bfr[FJ];
#pragma unroll
    for (int i = 0; i < FI; i++) {
      int row = rw + i * 16 + l16;
      af[i] = *(const short8*)(Sb + row * 32 + (grp ^ ((row >> 1) & 3)) * 8);
    }
#pragma unroll
    for (int j = 0; j < FJ; j++) {
      int row = cw + j * 16 + l16;
      bfr[j] = *(const short8*)(Sb + TM * 32 + row * 32 + (grp ^ ((row >> 1) & 3)) * 8);
    }
#pragma unroll
    for (int i = 0; i < FI; i++)
#pragma unroll
      for (int j = 0; j < FJ; j++)
        acc[i][j] = __builtin_amdgcn_mfma_f32_16x16x32_bf16(af[i], bfr[j], acc[i][j], 0, 0, 0);
  };

  // prologue: tiles 0,1,2 in flight; wait tile0 only (2 batches stay out)
  stage(0, 0);
  stage(1, 1);
  stage(2, 2);
  __builtin_amdgcn_sched_barrier(0);
  vm_wait<2 * NIT>();
  __builtin_amdgcn_sched_barrier(0);
  __builtin_amdgcn_s_barrier();
  __builtin_amdgcn_sched_barrier(0);

  // per step (BUF = buffer of tile just computed; after ++t, next compute
  // is tile t): stage tile t+2 into BUF if it exists, then wait per the
  // outstanding-set {t+1?, t+2?}: 2*NIT / NIT / 0.
#define GEMM_TAIL(BUF)                                                        \
  __builtin_amdgcn_s_barrier();                                               \
  __builtin_amdgcn_sched_barrier(0);                                          \
  if (t + 2 < nt) {                                                           \
    stage(t + 2, BUF);                                                        \
    __builtin_amdgcn_sched_barrier(0);                                        \
    vm_wait<2 * NIT>();                                                       \
  } else if (t + 1 < nt) {                                                    \
    vm_wait<NIT>();                                                           \
  } else {                                                                    \
    vm_wait<0>();                                                             \
  }                                                                           \
  __builtin_amdgcn_sched_barrier(0);                                          \
  __builtin_amdgcn_s_barrier();                                               \
  __builtin_amdgcn_sched_barrier(0);

  for (int t = 0;;) {
    compute(0);
    if (++t == nt) break;
    GEMM_TAIL(0)

    compute(1);
    if (++t == nt) break;
    GEMM_TAIL(1)

    compute(2);
    if (++t == nt) break;
    GEMM_TAIL(2)
  }
#undef GEMM_TAIL

  if constexpr (MODE == 2) {
    const int half = N >> 1;
#pragma unroll
    for (int i = 0; i < FI; i++) {
      const int mrow = m0 + rw + i * 16 + grp * 4;
#pragma unroll
      for (int j = 0; j < 2; j++) {
        const int gcol = (n0 >> 1) + (cw >> 1) + j * 16 + l16;
#pragma unroll
        for (int r = 0; r < 4; r++) {
          float a = acc[i][j][r];
          float bv = acc[i][j + 2][r];
          float ex = __builtin_amdgcn_exp2f(-a * 1.4426950408889634f);
          float s = a * __builtin_amdgcn_rcpf(1.0f + ex);
          Cb[(size_t)(mrow + r) * half + gcol] = f2bf(s * bv);
        }
      }
    }
  } else {
#pragma unroll
    for (int i = 0; i < FI; i++) {
#pragma unroll
      for (int j = 0; j < FJ; j++) {
        const int mrow = m0 + rw + i * 16 + grp * 4;
        const int ncol = n0 + cw + j * 16 + l16;
#pragma unroll
        for (int r = 0; r < 4; r++) {
          size_t idx = (size_t)(mrow + r) * N + ncol;
          float v = acc[i][j][r];
          if (MODE == 0) Cb[idx] = f2bf(v);
          else           Cf[idx] = v + Res[idx];
        }
      }
    }
  }
}

// ---------------------------------------------------------------- flash attention
// qkv: [NTOK][3072] bf16 ([3][H][64] per token). out: [NTOK][D] bf16.
// Block = 128 q-rows x one head x one batch; 8 WAVES (512 thr), each owns
// 16 q-rows (r11: +latency hiding, 337.9us total). Grid 512, LDS 54KB ->
// 2 blocks/CU = 16 waves/CU. 64-token KV chunks, K/V double-buffered, ONE
// barrier/chunk. Q direct from global. SWAPPED QK^T (S^T = mfma(K,Q));
// P packed b64 to Ps[q][k]; pad 76 (conflict-free, r10 measured 0).
// T5 setprio around MFMA. XCD remap: 4 (h,b) pairs/XCD for K/V L2 reuse.
__global__ __launch_bounds__(512, 2) void attn_flash(const uint16_t* __restrict__ qkv,
                                                     uint16_t* __restrict__ outp) {
  const int tid = threadIdx.x;
  const int w = tid >> 6, lane = tid & 63;
  const int grp = lane >> 4, l16 = lane & 15;
  const int lin = blockIdx.x;               // 512 blocks
  const int xcd = lin & 7;
  const int slot = lin >> 3;                // 0..63
  const int pair = xcd * 4 + (slot >> 4);   // 0..31
  const int qc = slot & 15;
  const int h = pair & 15, b = pair >> 4;
  const int q0 = qc * 128;

  __shared__ uint16_t Ks[2][4096];          // 64x64, XOR-swizzled 16B chunks
  __shared__ uint16_t Vt[2][64 * 76];       // V^T [d][t], pad 76
  __shared__ uint16_t Ps[128 * 76];         // P [q][k], pad 76, 16 rows/wave

  const size_t base = ((size_t)b * LSEQ) * 3072 + (size_t)h * 64;

  // ---- Q fragments straight from global (read once, 64B/lane)
  short8 aq[2];
  {
    const uint16_t* qr = qkv + base + (size_t)(q0 + w * 16 + l16) * 3072;
    aq[0] = *(const short8*)(qr + grp * 8);
    aq[1] = *(const short8*)(qr + 32 + grp * 8);
  }

  // ---- prologue: K0 (swizzled, async), V0 (VALU transpose)
  {
    int c = tid;
    int row = c >> 3, cc = (c & 7) ^ (row & 7);
    gl2lds16(qkv + base + (size_t)row * 3072 + 1024 + cc * 8, Ks[0] + c * 8);
  }
  {
    int c = tid;
    int tt = c & 63, db = c >> 6;
    uint4 vv = *(const uint4*)(qkv + base + (size_t)tt * 3072 + 2048 + db * 8);
    uint32_t uu[4] = {vv.x, vv.y, vv.z, vv.w};
#pragma unroll
    for (int e = 0; e < 4; e++) {
      Vt[0][(db * 8 + e * 2 + 0) * 76 + tt] = (uint16_t)(uu[e] & 0xFFFFu);
      Vt[0][(db * 8 + e * 2 + 1) * 76 + tt] = (uint16_t)(uu[e] >> 16);
    }
  }
  __syncthreads();

  float lsum = 0.0f;                        // row-sum for q = w*16 + l16
  floatx4 o_acc[4] = {};
  const float C = 0.125f * 1.4426950408889634f;   // 1/sqrt(64) * log2(e)

  for (int kc = 0; kc < LSEQ / 64; kc++) {
    const int cur = kc & 1, nxt = cur ^ 1;
    const bool pre = (kc + 1 < LSEQ / 64);
    const int t1 = (kc + 1) * 64;
    uint4 vv;
    if (pre) {
      // K prefetch: async direct-to-LDS into next buffer
      int c = tid;
      int row = c >> 3, cc = (c & 7) ^ (row & 7);
      gl2lds16(qkv + base + (size_t)(t1 + row) * 3072 + 1024 + cc * 8, Ks[nxt] + c * 8);
      // V prefetch into VGPRs (spilled to LDS after compute)
      int tt = c & 63, db = c >> 6;
      vv = *(const uint4*)(qkv + base + (size_t)(t1 + tt) * 3072 + 2048 + db * 8);
    }

    // ---- S^T = K Q^T from Ks[cur] (swapped operands)
    // s_acc[j]: lane holds S[q = w*16 + l16][k = j*16 + grp*4 + r]
    floatx4 s_acc[4] = {};
    __builtin_amdgcn_s_setprio(1);
#pragma unroll
    for (int j = 0; j < 4; j++) {
      const int krow = j * 16 + l16;
#pragma unroll
      for (int kk = 0; kk < 2; kk++) {
        int cc = kk * 4 + grp;
        short8 bk = *(const short8*)(Ks[cur] + (krow * 8 + (cc ^ (krow & 7))) * 8);
        s_acc[j] = __builtin_amdgcn_mfma_f32_16x16x32_bf16(bk, aq[kk], s_acc[j], 0, 0, 0);
      }
    }
    __builtin_amdgcn_s_setprio(0);

    // ---- p = 2^(s*C); per-lane row sums; packed b64 stores to Ps[q][k]
#pragma unroll
    for (int j = 0; j < 4; j++) {
      float p0 = __builtin_amdgcn_exp2f(s_acc[j][0] * C);
      float p1 = __builtin_amdgcn_exp2f(s_acc[j][1] * C);
      float p2 = __builtin_amdgcn_exp2f(s_acc[j][2] * C);
      float p3 = __builtin_amdgcn_exp2f(s_acc[j][3] * C);
      lsum += (p0 + p1) + (p2 + p3);
      uint2 pk;
      pk.x = cvt_pk_bf16(p0, p1);
      pk.y = cvt_pk_bf16(p2, p3);
      *(uint2*)(Ps + (w * 16 + l16) * 76 + j * 16 + grp * 4) = pk;
    }

    // ---- O += P V from Vt[cur] (wave-local Ps rows; same-wave LDS order)
    __builtin_amdgcn_s_setprio(1);
#pragma unroll
    for (int kk = 0; kk < 2; kk++) {
      short8 ap = *(const short8*)(Ps + (w * 16 + l16) * 76 + kk * 32 + grp * 8);
#pragma unroll
      for (int jj = 0; jj < 4; jj++) {
        short8 bv = *(const short8*)(Vt[cur] + (jj * 16 + l16) * 76 + kk * 32 + grp * 8);
        o_acc[jj] = __builtin_amdgcn_mfma_f32_16x16x32_bf16(ap, bv, o_acc[jj], 0, 0, 0);
      }
    }
    __builtin_amdgcn_s_setprio(0);

    // spill prefetched V into next buffer
    if (pre) {
      int c = tid;
      int tt = c & 63, db = c >> 6;
      uint32_t uu[4] = {vv.x, vv.y, vv.z, vv.w};
#pragma unroll
      for (int e = 0; e < 4; e++) {
        Vt[nxt][(db * 8 + e * 2 + 0) * 76 + tt] = (uint16_t)(uu[e] & 0xFFFFu);
        Vt[nxt][(db * 8 + e * 2 + 1) * 76 + tt] = (uint16_t)(uu[e] >> 16);
      }
    }
    __syncthreads();
  }

  // epilogue: reduce row sums across grp axis, redistribute, normalize, store
  lsum += __shfl_xor(lsum, 16, 64);
  lsum += __shfl_xor(lsum, 32, 64);
  // lane (grp,l16) needs lsum for q = w*16 + grp*4 + r -> from lane grp*4+r
  float lsr[4];
#pragma unroll
  for (int r = 0; r < 4; r++) lsr[r] = __shfl(lsum, grp * 4 + r, 64);
#pragma unroll
  for (int jj = 0; jj < 4; jj++)
#pragma unroll
    for (int r = 0; r < 4; r++) {
      int row = b * LSEQ + q0 + w * 16 + grp * 4 + r;
      float o = o_acc[jj][r] * __builtin_amdgcn_rcpf(lsr[r]);
      outp[(size_t)row * DMODEL + h * 64 + jj * 16 + l16] = f2bf(o);
    }
}

// ---------------------------------------------------------------- launch
extern "C" void kernel_launch(void* const* d_in, const int* in_sizes, int n_in,
                              void* d_out, int out_size, void* d_ws, size_t ws_size,
                              hipStream_t stream) {
  const float* x    = (const float*)d_in[0];
  const float* wqkv = (const float*)d_in[1];
  const float* wo   = (const float*)d_in[2];
  const float* n1w  = (const float*)d_in[3];
  const float* n2w  = (const float*)d_in[4];
  const float* w1   = (const float*)d_in[5];
  const float* w2   = (const float*)d_in[6];
  const float* w3   = (const float*)d_in[7];
  float* out = (float*)d_out;

  char* p = (char*)d_ws;
  uint16_t* wall  = (uint16_t*)p; p += (size_t)9728 * 1024 * 2;  // wqkv|wo|w13
  uint16_t* wqkvb = wall;
  uint16_t* wob   = wall + (size_t)3072 * 1024;
  uint16_t* w13b  = wall + (size_t)4096 * 1024;
  uint16_t* w2b   = (uint16_t*)p; p += (size_t)1024 * FFP * 2;
  uint16_t* h1    = (uint16_t*)p; p += (size_t)NTOK * DMODEL * 2;
  uint16_t* qkvb  = (uint16_t*)p; p += (size_t)NTOK * 3072 * 2;
  uint16_t* attno = (uint16_t*)p; p += (size_t)NTOK * DMODEL * 2;
  float*    x1    = (float*)p;    p += (size_t)NTOK * DMODEL * 4;
  uint16_t* h2    = (uint16_t*)p; p += (size_t)NTOK * DMODEL * 2;
  uint16_t* gbuf  = (uint16_t*)p; p += (size_t)NTOK * FFP * 2;

  cvt_all_k<<<9728, 256, 0, stream>>>(wqkv, wo, w1, w3, wall);
  cvt_pad_k<<<(1024 * (FFP / 4)) / 256, 256, 0, stream>>>(w2, w2b, 1024, FFR, FFP);

  rmsnorm_k<<<NTOK, 256, 0, stream>>>(x, n1w, h1);
  gemm_bt<0, 128, 128><<<dim3(3072 / 128, NTOK / 128), 256, 0, stream>>>(
      h1, wqkvb, qkvb, nullptr, nullptr, NTOK, 3072, 1024);
  attn_flash<<<512, 512, 0, stream>>>(qkvb, attno);
  gemm_bt<1, 128, 64><<<dim3(1024 / 64, NTOK / 128), 256, 0, stream>>>(
      attno, wob, nullptr, x1, x, NTOK, 1024, 1024);
  rmsnorm_k<<<NTOK, 256, 0, stream>>>(x1, n2w, h2);
  gemm_bt<2, 128, 128><<<dim3(FF2 / 128, NTOK / 128), 256, 0, stream>>>(
      h2, w13b, gbuf, nullptr, nullptr, NTOK, FF2, 1024);
  gemm_bt<1, 128, 64><<<dim3(1024 / 64, NTOK / 128), 256, 0, stream>>>(
      gbuf, w2b, nullptr, out, x1, NTOK, 1024, FFP);
}

// Round 14
// 334.502 us; speedup vs baseline: 1.0352x; 1.0020x over previous
//
#include <hip/hip_runtime.h>
#include <stdint.h>

// Transformer block: x + attn(rmsnorm(x)) then + swiglu(rmsnorm(.))
// bf16 MFMA (16x16x32), fp32 accumulate, fp32 residuals.
// B=2, L=2048, D=1024, H=16, DK=64, FF=2730 (padded to 2816).

#define LSEQ   2048
#define DMODEL 1024
#define NHEAD  16
#define NTOK   4096
#define FFR    2730
#define FFP    2816
#define FF2    5632          // w1|w3 fused N (interleaved in 32-row units)

typedef short  short8  __attribute__((ext_vector_type(8)));
typedef float  floatx4 __attribute__((ext_vector_type(4)));

__device__ __forceinline__ uint16_t f2bf(float f) {
  uint32_t u = __builtin_bit_cast(uint32_t, f);
  u += 0x7FFFu + ((u >> 16) & 1u);          // RNE
  return (uint16_t)(u >> 16);
}
// v_cvt_pk_bf16_f32: low=a, high=b. Proven bit-identical to explicit RNE pack.
__device__ __forceinline__ uint32_t cvt_pk_bf16(float a, float b) {
  uint32_t d;
  asm("v_cvt_pk_bf16_f32 %0, %1, %2" : "=v"(d) : "v"(a), "v"(b));
  return d;
}
__device__ __forceinline__ void gl2lds16(const void* g, void* l) {
  __builtin_amdgcn_global_load_lds(
      (const __attribute__((address_space(1))) unsigned int*)g,
      (__attribute__((address_space(3))) unsigned int*)l, 16, 0, 0);
}
// counted VMEM wait (T4). Literal-only asm string, if constexpr dispatch.
template <int N>
__device__ __forceinline__ void vm_wait() {
  if constexpr (N == 0)       asm volatile("s_waitcnt vmcnt(0)" ::: "memory");
  else if constexpr (N == 3)  asm volatile("s_waitcnt vmcnt(3)" ::: "memory");
  else if constexpr (N == 4)  asm volatile("s_waitcnt vmcnt(4)" ::: "memory");
  else if constexpr (N == 6)  asm volatile("s_waitcnt vmcnt(6)" ::: "memory");
  else if constexpr (N == 8)  asm volatile("s_waitcnt vmcnt(8)" ::: "memory");
  else if constexpr (N == 12) asm volatile("s_waitcnt vmcnt(12)" ::: "memory");
}

// ------------------------------------------------ fused weight convert
// dst rows: [0,3072) wqkv | [3072,4096) wo |
// [4096,9728) w13 interleaved: unit u (64 rows) = [w1 rows u*32..+31 | w3 rows u*32..+31]
__global__ __launch_bounds__(256) void cvt_all_k(const float* __restrict__ wqkv,
                                                 const float* __restrict__ wo,
                                                 const float* __restrict__ w1,
                                                 const float* __restrict__ w3,
                                                 uint16_t* __restrict__ dst) {
  int g = blockIdx.x;                 // one row (1024 cols) per block
  int c = threadIdx.x * 4;
  const float* src = nullptr;
  if (g < 3072)       src = wqkv + (size_t)g * 1024;
  else if (g < 4096)  src = wo + (size_t)(g - 3072) * 1024;
  else {
    int r = g - 4096;                 // 0..5631
    int u = r >> 6, wi = r & 63;
    int srow = u * 32 + (wi & 31);
    if (srow < FFR) src = ((wi < 32) ? w1 : w3) + (size_t)srow * 1024;
  }
  float4 v = src ? *(const float4*)(src + c) : float4{0, 0, 0, 0};
  uint64_t pack =  (uint64_t)f2bf(v.x)        | ((uint64_t)f2bf(v.y) << 16)
                | ((uint64_t)f2bf(v.z) << 32) | ((uint64_t)f2bf(v.w) << 48);
  *(uint64_t*)(dst + (size_t)g * 1024 + c) = pack;
}

// w2 needs column padding 2730->2816; 4 cols/thread, uint64 store.
__global__ __launch_bounds__(256) void cvt_pad_k(const float* __restrict__ src,
                                                 uint16_t* __restrict__ dst,
                                                 int rows, int cols, int cols_p) {
  long idx = (long)blockIdx.x * 256 + threadIdx.x;   // one per 4 cols
  int c4 = cols_p >> 2;
  if (idx >= (long)rows * c4) return;
  int r = (int)(idx / c4);
  int c = (int)(idx % c4) * 4;
  uint64_t pack;
  if (c + 3 < cols) {
    const float* sp = src + (size_t)r * cols + c;
    float2 a = *(const float2*)sp;
    float2 b2 = *(const float2*)(sp + 2);
    pack =  (uint64_t)f2bf(a.x)        | ((uint64_t)f2bf(a.y) << 16)
         | ((uint64_t)f2bf(b2.x) << 32) | ((uint64_t)f2bf(b2.y) << 48);
  } else {
    pack = 0;
    for (int e = 0; e < 4; e++) {
      float v = (c + e < cols) ? src[(size_t)r * cols + c + e] : 0.0f;
      pack |= (uint64_t)f2bf(v) << (16 * e);
    }
  }
  *(uint64_t*)(dst + (size_t)r * cols_p + c) = pack;
}

// ---------------------------------------------------------------- rmsnorm
__global__ __launch_bounds__(256) void rmsnorm_k(const float* __restrict__ x,
                                                 const float* __restrict__ wgt,
                                                 uint16_t* __restrict__ out) {
  const int row = blockIdx.x;
  const int c = threadIdx.x * 4;
  const float* xr = x + (size_t)row * DMODEL;
  float4 v = *(const float4*)(xr + c);
  float ss = v.x * v.x + v.y * v.y + v.z * v.z + v.w * v.w;
#pragma unroll
  for (int off = 32; off >= 1; off >>= 1) ss += __shfl_down(ss, off, 64);
  __shared__ float red[4];
  if ((threadIdx.x & 63) == 0) red[threadIdx.x >> 6] = ss;
  __syncthreads();
  float tot = red[0] + red[1] + red[2] + red[3];
  float scale = rsqrtf(tot * (1.0f / DMODEL) + 1e-6f);
  float4 wv = *(const float4*)(wgt + c);
  uint64_t pack =  (uint64_t)f2bf(v.x * scale * wv.x)
                | ((uint64_t)f2bf(v.y * scale * wv.y) << 16)
                | ((uint64_t)f2bf(v.z * scale * wv.z) << 32)
                | ((uint64_t)f2bf(v.w * scale * wv.w) << 48);
  *(uint64_t*)(out + (size_t)row * DMODEL + c) = pack;
}

// ---------------------------------------------------------------- GEMM
// C[M,N] = A[M,K](bf16,row) @ B[N,K](bf16,row)^T ; 4 waves (2x2), wave tile
// (TM/2)x(TN/2). r13 diagnosis: 64x64 wave tile is LDS-read-bound
// (LDS 1156 cyc vs MFMA 774 cyc per K-step/CU) -> TM=256 gives 128x64 wave
// tile: 12 b128 reads feed 32 MFMAs (ratio 1.49 -> 1.12). acc = 128 VGPR,
// __launch_bounds__(256,2) -> 2 waves/SIMD, 2 blocks/CU (LDS 72KB).
// MODE 0: bf16 store. MODE 1: fp32 Cf = acc + Res. MODE 2: fused swiglu
// (wave's 64-col span = one w1/w3 interleave unit; j/j+2 pairing intact).
// T4 pipeline DEPTH 3 (counted vmcnt), r13-proven; LDS chunk XOR swizzle
// (conflicts 5.77M -> 0 measured r13). K-iteration order unchanged.
template <int MODE, int TM, int TN>
__global__ __launch_bounds__(256, 2) void gemm_bt(const uint16_t* __restrict__ A,
                                                  const uint16_t* __restrict__ B,
                                                  uint16_t* __restrict__ Cb,
                                                  float* __restrict__ Cf,
                                                  const float* __restrict__ Res,
                                                  int M, int N, int K) {
  constexpr int FI = TM / 32, FJ = TN / 32;
  constexpr int NIT = (TM + TN) / 64;
  constexpr int BUFO = (TM + TN) * 32;       // uint16 elems per buffer
  __shared__ uint16_t S[3 * BUFO];           // [buf][A(TM*32) | B(TN*32)]
  const int tid = threadIdx.x;
  const int w = tid >> 6, lane = tid & 63;
  const int grp = lane >> 4, l16 = lane & 15;
  const int m0 = blockIdx.y * TM, n0 = blockIdx.x * TN;
  const int rw = (w >> 1) * (TM / 2), cw = (w & 1) * (TN / 2);

  floatx4 acc[FI][FJ] = {};

  const uint16_t* gp[NIT];
  uint16_t* lp[NIT];
#pragma unroll
  for (int i = 0; i < NIT; i++) {
    int c = i * 256 + tid;
    if (c < TM * 4) {
      int row = c >> 2, ch = c & 3;
      gp[i] = A + (size_t)(m0 + row) * K + (ch ^ ((row >> 1) & 3)) * 8;
      lp[i] = S + c * 8;
    } else {
      int c2 = c - TM * 4;
      int row = c2 >> 2, ch = c2 & 3;
      gp[i] = B + (size_t)(n0 + row) * K + (ch ^ ((row >> 1) & 3)) * 8;
      lp[i] = S + TM * 32 + c2 * 8;
    }
  }

  const int nt = K / 32;                     // >= 3 for all call sites

  auto stage = [&](int t, int buf) {
#pragma unroll
    for (int i = 0; i < NIT; i++) gl2lds16(gp[i] + t * 32, lp[i] + buf * BUFO);
  };
  auto compute = [&](int buf) {
    const uint16_t* Sb = S + buf * BUFO;
    short8 af[FI], bfr[FJ];
#pragma unroll
    for (int i = 0; i < FI; i++) {
      int row = rw + i * 16 + l16;
      af[i] = *(const short8*)(Sb + row * 32 + (grp ^ ((row >> 1) & 3)) * 8);
    }
#pragma unroll
    for (int j = 0; j < FJ; j++) {
      int row = cw + j * 16 + l16;
      bfr[j] = *(const short8*)(Sb + TM * 32 + row * 32 + (grp ^ ((row >> 1) & 3)) * 8);
    }
#pragma unroll
    for (int i = 0; i < FI; i++)
#pragma unroll
      for (int j = 0; j < FJ; j++)
        acc[i][j] = __builtin_amdgcn_mfma_f32_16x16x32_bf16(af[i], bfr[j], acc[i][j], 0, 0, 0);
  };

  // prologue: tiles 0,1,2 in flight; wait tile0 only (2 batches stay out)
  stage(0, 0);
  stage(1, 1);
  stage(2, 2);
  __builtin_amdgcn_sched_barrier(0);
  vm_wait<2 * NIT>();
  __builtin_amdgcn_sched_barrier(0);
  __builtin_amdgcn_s_barrier();
  __builtin_amdgcn_sched_barrier(0);

  // per step (BUF = buffer of tile just computed; after ++t, next compute
  // is tile t): stage tile t+2 into BUF if it exists, then wait per the
  // outstanding-set {t+1?, t+2?}: 2*NIT / NIT / 0.
#define GEMM_TAIL(BUF)                                                        \
  __builtin_amdgcn_s_barrier();                                               \
  __builtin_amdgcn_sched_barrier(0);                                          \
  if (t + 2 < nt) {                                                           \
    stage(t + 2, BUF);                                                        \
    __builtin_amdgcn_sched_barrier(0);                                        \
    vm_wait<2 * NIT>();                                                       \
  } else if (t + 1 < nt) {                                                    \
    vm_wait<NIT>();                                                           \
  } else {                                                                    \
    vm_wait<0>();                                                             \
  }                                                                           \
  __builtin_amdgcn_sched_barrier(0);                                          \
  __builtin_amdgcn_s_barrier();                                               \
  __builtin_amdgcn_sched_barrier(0);

  for (int t = 0;;) {
    compute(0);
    if (++t == nt) break;
    GEMM_TAIL(0)

    compute(1);
    if (++t == nt) break;
    GEMM_TAIL(1)

    compute(2);
    if (++t == nt) break;
    GEMM_TAIL(2)
  }
#undef GEMM_TAIL

  if constexpr (MODE == 2) {
    const int half = N >> 1;
#pragma unroll
    for (int i = 0; i < FI; i++) {
      const int mrow = m0 + rw + i * 16 + grp * 4;
#pragma unroll
      for (int j = 0; j < 2; j++) {
        const int gcol = (n0 >> 1) + (cw >> 1) + j * 16 + l16;
#pragma unroll
        for (int r = 0; r < 4; r++) {
          float a = acc[i][j][r];
          float bv = acc[i][j + 2][r];
          float ex = __builtin_amdgcn_exp2f(-a * 1.4426950408889634f);
          float s = a * __builtin_amdgcn_rcpf(1.0f + ex);
          Cb[(size_t)(mrow + r) * half + gcol] = f2bf(s * bv);
        }
      }
    }
  } else {
#pragma unroll
    for (int i = 0; i < FI; i++) {
#pragma unroll
      for (int j = 0; j < FJ; j++) {
        const int mrow = m0 + rw + i * 16 + grp * 4;
        const int ncol = n0 + cw + j * 16 + l16;
#pragma unroll
        for (int r = 0; r < 4; r++) {
          size_t idx = (size_t)(mrow + r) * N + ncol;
          float v = acc[i][j][r];
          if (MODE == 0) Cb[idx] = f2bf(v);
          else           Cf[idx] = v + Res[idx];
        }
      }
    }
  }
}

// ---------------------------------------------------------------- flash attention
// qkv: [NTOK][3072] bf16 ([3][H][64] per token). out: [NTOK][D] bf16.
// Block = 128 q-rows x one head x one batch; 8 WAVES (512 thr), each owns
// 16 q-rows (r11: +latency hiding, 337.9us total). Grid 512, LDS 54KB ->
// 2 blocks/CU = 16 waves/CU. 64-token KV chunks, K/V double-buffered, ONE
// barrier/chunk. Q direct from global. SWAPPED QK^T (S^T = mfma(K,Q));
// P packed b64 to Ps[q][k]; pad 76 (conflict-free, r10 measured 0).
// T5 setprio around MFMA. XCD remap: 4 (h,b) pairs/XCD for K/V L2 reuse.
__global__ __launch_bounds__(512, 2) void attn_flash(const uint16_t* __restrict__ qkv,
                                                     uint16_t* __restrict__ outp) {
  const int tid = threadIdx.x;
  const int w = tid >> 6, lane = tid & 63;
  const int grp = lane >> 4, l16 = lane & 15;
  const int lin = blockIdx.x;               // 512 blocks
  const int xcd = lin & 7;
  const int slot = lin >> 3;                // 0..63
  const int pair = xcd * 4 + (slot >> 4);   // 0..31
  const int qc = slot & 15;
  const int h = pair & 15, b = pair >> 4;
  const int q0 = qc * 128;

  __shared__ uint16_t Ks[2][4096];          // 64x64, XOR-swizzled 16B chunks
  __shared__ uint16_t Vt[2][64 * 76];       // V^T [d][t], pad 76
  __shared__ uint16_t Ps[128 * 76];         // P [q][k], pad 76, 16 rows/wave

  const size_t base = ((size_t)b * LSEQ) * 3072 + (size_t)h * 64;

  // ---- Q fragments straight from global (read once, 64B/lane)
  short8 aq[2];
  {
    const uint16_t* qr = qkv + base + (size_t)(q0 + w * 16 + l16) * 3072;
    aq[0] = *(const short8*)(qr + grp * 8);
    aq[1] = *(const short8*)(qr + 32 + grp * 8);
  }

  // ---- prologue: K0 (swizzled, async), V0 (VALU transpose)
  {
    int c = tid;
    int row = c >> 3, cc = (c & 7) ^ (row & 7);
    gl2lds16(qkv + base + (size_t)row * 3072 + 1024 + cc * 8, Ks[0] + c * 8);
  }
  {
    int c = tid;
    int tt = c & 63, db = c >> 6;
    uint4 vv = *(const uint4*)(qkv + base + (size_t)tt * 3072 + 2048 + db * 8);
    uint32_t uu[4] = {vv.x, vv.y, vv.z, vv.w};
#pragma unroll
    for (int e = 0; e < 4; e++) {
      Vt[0][(db * 8 + e * 2 + 0) * 76 + tt] = (uint16_t)(uu[e] & 0xFFFFu);
      Vt[0][(db * 8 + e * 2 + 1) * 76 + tt] = (uint16_t)(uu[e] >> 16);
    }
  }
  __syncthreads();

  float lsum = 0.0f;                        // row-sum for q = w*16 + l16
  floatx4 o_acc[4] = {};
  const float C = 0.125f * 1.4426950408889634f;   // 1/sqrt(64) * log2(e)

  for (int kc = 0; kc < LSEQ / 64; kc++) {
    const int cur = kc & 1, nxt = cur ^ 1;
    const bool pre = (kc + 1 < LSEQ / 64);
    const int t1 = (kc + 1) * 64;
    uint4 vv;
    if (pre) {
      // K prefetch: async direct-to-LDS into next buffer
      int c = tid;
      int row = c >> 3, cc = (c & 7) ^ (row & 7);
      gl2lds16(qkv + base + (size_t)(t1 + row) * 3072 + 1024 + cc * 8, Ks[nxt] + c * 8);
      // V prefetch into VGPRs (spilled to LDS after compute)
      int tt = c & 63, db = c >> 6;
      vv = *(const uint4*)(qkv + base + (size_t)(t1 + tt) * 3072 + 2048 + db * 8);
    }

    // ---- S^T = K Q^T from Ks[cur] (swapped operands)
    // s_acc[j]: lane holds S[q = w*16 + l16][k = j*16 + grp*4 + r]
    floatx4 s_acc[4] = {};
    __builtin_amdgcn_s_setprio(1);
#pragma unroll
    for (int j = 0; j < 4; j++) {
      const int krow = j * 16 + l16;
#pragma unroll
      for (int kk = 0; kk < 2; kk++) {
        int cc = kk * 4 + grp;
        short8 bk = *(const short8*)(Ks[cur] + (krow * 8 + (cc ^ (krow & 7))) * 8);
        s_acc[j] = __builtin_amdgcn_mfma_f32_16x16x32_bf16(bk, aq[kk], s_acc[j], 0, 0, 0);
      }
    }
    __builtin_amdgcn_s_setprio(0);

    // ---- p = 2^(s*C); per-lane row sums; packed b64 stores to Ps[q][k]
#pragma unroll
    for (int j = 0; j < 4; j++) {
      float p0 = __builtin_amdgcn_exp2f(s_acc[j][0] * C);
      float p1 = __builtin_amdgcn_exp2f(s_acc[j][1] * C);
      float p2 = __builtin_amdgcn_exp2f(s_acc[j][2] * C);
      float p3 = __builtin_amdgcn_exp2f(s_acc[j][3] * C);
      lsum += (p0 + p1) + (p2 + p3);
      uint2 pk;
      pk.x = cvt_pk_bf16(p0, p1);
      pk.y = cvt_pk_bf16(p2, p3);
      *(uint2*)(Ps + (w * 16 + l16) * 76 + j * 16 + grp * 4) = pk;
    }

    // ---- O += P V from Vt[cur] (wave-local Ps rows; same-wave LDS order)
    __builtin_amdgcn_s_setprio(1);
#pragma unroll
    for (int kk = 0; kk < 2; kk++) {
      short8 ap = *(const short8*)(Ps + (w * 16 + l16) * 76 + kk * 32 + grp * 8);
#pragma unroll
      for (int jj = 0; jj < 4; jj++) {
        short8 bv = *(const short8*)(Vt[cur] + (jj * 16 + l16) * 76 + kk * 32 + grp * 8);
        o_acc[jj] = __builtin_amdgcn_mfma_f32_16x16x32_bf16(ap, bv, o_acc[jj], 0, 0, 0);
      }
    }
    __builtin_amdgcn_s_setprio(0);

    // spill prefetched V into next buffer
    if (pre) {
      int c = tid;
      int tt = c & 63, db = c >> 6;
      uint32_t uu[4] = {vv.x, vv.y, vv.z, vv.w};
#pragma unroll
      for (int e = 0; e < 4; e++) {
        Vt[nxt][(db * 8 + e * 2 + 0) * 76 + tt] = (uint16_t)(uu[e] & 0xFFFFu);
        Vt[nxt][(db * 8 + e * 2 + 1) * 76 + tt] = (uint16_t)(uu[e] >> 16);
      }
    }
    __syncthreads();
  }

  // epilogue: reduce row sums across grp axis, redistribute, normalize, store
  lsum += __shfl_xor(lsum, 16, 64);
  lsum += __shfl_xor(lsum, 32, 64);
  // lane (grp,l16) needs lsum for q = w*16 + grp*4 + r -> from lane grp*4+r
  float lsr[4];
#pragma unroll
  for (int r = 0; r < 4; r++) lsr[r] = __shfl(lsum, grp * 4 + r, 64);
#pragma unroll
  for (int jj = 0; jj < 4; jj++)
#pragma unroll
    for (int r = 0; r < 4; r++) {
      int row = b * LSEQ + q0 + w * 16 + grp * 4 + r;
      float o = o_acc[jj][r] * __builtin_amdgcn_rcpf(lsr[r]);
      outp[(size_t)row * DMODEL + h * 64 + jj * 16 + l16] = f2bf(o);
    }
}

// ---------------------------------------------------------------- launch
extern "C" void kernel_launch(void* const* d_in, const int* in_sizes, int n_in,
                              void* d_out, int out_size, void* d_ws, size_t ws_size,
                              hipStream_t stream) {
  const float* x    = (const float*)d_in[0];
  const float* wqkv = (const float*)d_in[1];
  const float* wo   = (const float*)d_in[2];
  const float* n1w  = (const float*)d_in[3];
  const float* n2w  = (const float*)d_in[4];
  const float* w1   = (const float*)d_in[5];
  const float* w2   = (const float*)d_in[6];
  const float* w3   = (const float*)d_in[7];
  float* out = (float*)d_out;

  char* p = (char*)d_ws;
  uint16_t* wall  = (uint16_t*)p; p += (size_t)9728 * 1024 * 2;  // wqkv|wo|w13
  uint16_t* wqkvb = wall;
  uint16_t* wob   = wall + (size_t)3072 * 1024;
  uint16_t* w13b  = wall + (size_t)4096 * 1024;
  uint16_t* w2b   = (uint16_t*)p; p += (size_t)1024 * FFP * 2;
  uint16_t* h1    = (uint16_t*)p; p += (size_t)NTOK * DMODEL * 2;
  uint16_t* qkvb  = (uint16_t*)p; p += (size_t)NTOK * 3072 * 2;
  uint16_t* attno = (uint16_t*)p; p += (size_t)NTOK * DMODEL * 2;
  float*    x1    = (float*)p;    p += (size_t)NTOK * DMODEL * 4;
  uint16_t* h2    = (uint16_t*)p; p += (size_t)NTOK * DMODEL * 2;
  uint16_t* gbuf  = (uint16_t*)p; p += (size_t)NTOK * FFP * 2;

  cvt_all_k<<<9728, 256, 0, stream>>>(wqkv, wo, w1, w3, wall);
  cvt_pad_k<<<(1024 * (FFP / 4)) / 256, 256, 0, stream>>>(w2, w2b, 1024, FFR, FFP);

  rmsnorm_k<<<NTOK, 256, 0, stream>>>(x, n1w, h1);
  gemm_bt<0, 256, 128><<<dim3(3072 / 128, NTOK / 256), 256, 0, stream>>>(
      h1, wqkvb, qkvb, nullptr, nullptr, NTOK, 3072, 1024);
  attn_flash<<<512, 512, 0, stream>>>(qkvb, attno);
  gemm_bt<1, 128, 64><<<dim3(1024 / 64, NTOK / 128), 256, 0, stream>>>(
      attno, wob, nullptr, x1, x, NTOK, 1024, 1024);
  rmsnorm_k<<<NTOK, 256, 0, stream>>>(x1, n2w, h2);
  gemm_bt<2, 256, 128><<<dim3(FF2 / 128, NTOK / 256), 256, 0, stream>>>(
      h2, w13b, gbuf, nullptr, nullptr, NTOK, FF2, 1024);
  gemm_bt<1, 128, 64><<<dim3(1024 / 64, NTOK / 128), 256, 0, stream>>>(
      gbuf, w2b, nullptr, out, x1, NTOK, 1024, FFP);
}